// Round 15
// baseline (3288.768 us; speedup 1.0000x reference)
//
#include <hip/hip_runtime.h>

typedef unsigned short u16;
typedef __attribute__((ext_vector_type(8))) short short8;
typedef __attribute__((ext_vector_type(4))) float f32x4;

#define NTOK 6304   // 32*197
#define SP 197

// ---- workspace offsets (bytes) ----
#define OFF_WQKVT 0L
#define OFF_WOT   42467328L
#define OFF_W1T   56623104L
#define OFF_W2T   113246208L
#define OFF_WPT   169869312L
#define OFF_BQKV  171048960L
#define OFF_H     171159552L
#define OFF_XN    190525440L
#define OFF_QKV   200208384L
#define OFF_SC    229257216L
#define OFF_PM1   288867840L
#define OFF_VT    327599616L
#define OFF_CN    340182528L
#define OFF_T1    340280832L
#define WS_NEEDED 340379136L

__device__ __forceinline__ u16 f2bf(float x) {
  unsigned int u = __float_as_uint(x);
  u += 0x7fffu + ((u >> 16) & 1u);
  return (u16)(u >> 16);
}

__device__ __forceinline__ float gelu_f(float x) {
  return 0.5f * x * (1.0f + erff(x * 0.70710678118654752f));
}

__device__ __forceinline__ void gload_lds16(const void* g, void* l) {
  __builtin_amdgcn_global_load_lds(
      (const __attribute__((address_space(1))) unsigned int*)g,
      (__attribute__((address_space(3))) unsigned int*)l, 16, 0, 0);
}

// ============================================================================
// gemm_k: m97-structure 128^2 single-buffer GEMM (r8/r13-proven) + bijective
// XCD swizzle. For qkv (900 blocks, 4 waves: best measured for that site).
// ============================================================================
template <bool BIAS, bool GELU, bool RES, bool OBF16, bool REMAP>
__global__ __launch_bounds__(256, 3) void gemm_k(
    const u16* __restrict__ A, int lda,
    const u16* __restrict__ Bm, int ldb,
    void* Cv, int ldc,
    const float* __restrict__ bias, const float* res, int ldres,
    int M, int N, int K, int tilesN) {
  __shared__ float4 smemv[2048];
  char* smem = (char*)smemv;

  const int t = threadIdx.x;
  const int nwg = gridDim.x;
  const int orig = blockIdx.x;
  const int q8 = nwg >> 3, r8 = nwg & 7;
  const int xcd = orig & 7, loc = orig >> 3;
  const int wg =
      (xcd < r8 ? xcd * (q8 + 1) : r8 * (q8 + 1) + (xcd - r8) * q8) + loc;
  const int tn = wg % tilesN, tm = wg / tilesN;
  const int m0 = tm * 128, n0 = tn * 128;
  const int l = t & 63;
  const int lr = l & 15, kb = l >> 4;
  const int wr = (t >> 7) & 1, wc = (t >> 6) & 1;

  const f32x4 zf = {0.f, 0.f, 0.f, 0.f};
  f32x4 acc[4][4];
#pragma unroll
  for (int m = 0; m < 4; ++m)
#pragma unroll
    for (int n = 0; n < 4; ++n) acc[m][n] = zf;

  auto stage = [&](const u16* src, int ld, int row0, int maxrow, int k0,
                   char* ldsbase) {
#pragma unroll
    for (int p = 0; p < 4; ++p) {
      int idx = p * 256 + t;
      int r = idx >> 3;
      int cl = idx & 7;
      int cg = cl ^ (r & 7);
      int rr = row0 + r;
      rr = rr > maxrow ? maxrow : rr;
      gload_lds16(src + (long)rr * ld + k0 + cg * 8,
                  ldsbase + (long)(p * 256 + (t & ~63)) * 16);
    }
  };

  const int KT = K >> 6;
  for (int kt = 0; kt < KT; ++kt) {
    stage(A, lda, m0, M - 1, kt * 64, smem);
    stage(Bm, ldb, n0, N - 1, kt * 64, smem + 16384);
    __syncthreads();
    const char* Ab = smem;
    const char* Bb = smem + 16384;
#pragma unroll
    for (int kk = 0; kk < 2; ++kk) {
      const int cla = ((kk << 2) + kb) ^ (lr & 7);
      short8 af[4], bfv[4];
#pragma unroll
      for (int m = 0; m < 4; ++m)
        af[m] = *(const short8*)(Ab + ((wr * 64 + m * 16 + lr) * 128 + cla * 16));
#pragma unroll
      for (int n = 0; n < 4; ++n)
        bfv[n] = *(const short8*)(Bb + ((wc * 64 + n * 16 + lr) * 128 + cla * 16));
#pragma unroll
      for (int m = 0; m < 4; ++m)
#pragma unroll
        for (int n = 0; n < 4; ++n)
          acc[m][n] = __builtin_amdgcn_mfma_f32_16x16x32_bf16(af[m], bfv[n],
                                                              acc[m][n], 0, 0, 0);
    }
    __syncthreads();
  }

#pragma unroll
  for (int n = 0; n < 4; ++n) {
    const int gc = n0 + wc * 64 + n * 16 + lr;
    if (gc >= N) continue;
    const float bv = BIAS ? bias[gc] : 0.0f;
#pragma unroll
    for (int m = 0; m < 4; ++m) {
#pragma unroll
      for (int j = 0; j < 4; ++j) {
        const int gr = m0 + wr * 64 + m * 16 + kb * 4 + j;
        if (gr >= M) continue;
        float v = acc[m][n][j] + bv;
        if (RES) v += res[(long)gr * ldres + gc];
        if (GELU) v = gelu_f(v);
        long orow = gr;
        if (REMAP) orow = (long)(gr / 196) * 197 + (gr % 196) + 1;
        if (OBF16)
          ((u16*)Cv)[orow * (long)ldc + gc] = f2bf(v);
        else
          ((float*)Cv)[orow * (long)ldc + gc] = v;
      }
    }
  }
}

// ============================================================================
// gemm_w: 256x128 single-buffer GEMM, 8 waves, 48KB LDS (r14: fc1 measured
// 99.5us vs gemm_k 105.2 — per-dispatch A/B). For fc1 only.
// ============================================================================
template <bool BIAS, bool GELU, bool RES, bool OBF16, bool REMAP>
__global__ __launch_bounds__(512, 2) void gemm_w(
    const u16* __restrict__ A, int lda,
    const u16* __restrict__ Bm, int ldb,
    void* Cv, int ldc,
    const float* __restrict__ bias, const float* res, int ldres,
    int M, int N, int K, int tilesN) {
  __shared__ __align__(16) char smem[49152];  // A 32KB + B 16KB

  const int t = threadIdx.x;
  const int l = t & 63;
  const int lr = l & 15, kb = (l >> 4) & 3;
  const int wid = t >> 6;
  const int wr = wid >> 1;
  const int wc = wid & 1;

  const int nwg = gridDim.x;
  const int orig = blockIdx.x;
  const int q8 = nwg >> 3, r8 = nwg & 7;
  const int xcd = orig & 7, loc = orig >> 3;
  const int wg =
      (xcd < r8 ? xcd * (q8 + 1) : r8 * (q8 + 1) + (xcd - r8) * q8) + loc;
  const int tn = wg % tilesN, tm = wg / tilesN;
  const int m0 = tm * 256, n0 = tn * 128;
  const int Mm1 = M - 1, Nm1 = N - 1;

  const f32x4 zf = {0.f, 0.f, 0.f, 0.f};
  f32x4 acc[4][4];
#pragma unroll
  for (int m = 0; m < 4; ++m)
#pragma unroll
    for (int n = 0; n < 4; ++n) acc[m][n] = zf;

  auto stage = [&](int k0) {
#pragma unroll
    for (int p = 0; p < 4; ++p) {
      int idx = p * 512 + t;
      int r = idx >> 3, cl = idx & 7;
      int cg = cl ^ (r & 7);
      int rr = m0 + r;
      rr = rr > Mm1 ? Mm1 : rr;
      gload_lds16(A + (long)rr * lda + k0 + cg * 8,
                  smem + ((p * 512 + (t & ~63)) << 4));
    }
#pragma unroll
    for (int p = 0; p < 2; ++p) {
      int idx = p * 512 + t;
      int r = idx >> 3, cl = idx & 7;
      int cg = cl ^ (r & 7);
      int rr = n0 + r;
      rr = rr > Nm1 ? Nm1 : rr;
      gload_lds16(Bm + (long)rr * ldb + k0 + cg * 8,
                  smem + 32768 + ((p * 512 + (t & ~63)) << 4));
    }
  };

  const int KT = K >> 6;
  for (int kt = 0; kt < KT; ++kt) {
    stage(kt * 64);
    __syncthreads();
    const char* Ab = smem;
    const char* Bb = smem + 32768;
#pragma unroll
    for (int kk = 0; kk < 2; ++kk) {
      const int ch = ((((kk << 2) | kb) ^ (lr & 7)) << 4);
      short8 af[4], bfv[4];
#pragma unroll
      for (int m = 0; m < 4; ++m)
        af[m] = *(const short8*)(Ab + (wr * 64 + m * 16 + lr) * 128 + ch);
#pragma unroll
      for (int n = 0; n < 4; ++n)
        bfv[n] = *(const short8*)(Bb + (wc * 64 + n * 16 + lr) * 128 + ch);
#pragma unroll
      for (int m = 0; m < 4; ++m)
#pragma unroll
        for (int n = 0; n < 4; ++n)
          acc[m][n] = __builtin_amdgcn_mfma_f32_16x16x32_bf16(af[m], bfv[n],
                                                              acc[m][n], 0, 0, 0);
    }
    __syncthreads();
  }

#pragma unroll
  for (int n = 0; n < 4; ++n) {
    const int gc = n0 + wc * 64 + n * 16 + lr;
    if (gc >= N) continue;
    const float bv = BIAS ? bias[gc] : 0.0f;
#pragma unroll
    for (int m = 0; m < 4; ++m) {
#pragma unroll
      for (int j = 0; j < 4; ++j) {
        const int gr = m0 + wr * 64 + m * 16 + kb * 4 + j;
        if (gr >= M) continue;
        float v = acc[m][n][j] + bv;
        if (RES) v += res[(long)gr * ldres + gc];
        if (GELU) v = gelu_f(v);
        long orow = gr;
        if (REMAP) orow = (long)(gr / 196) * 197 + (gr % 196) + 1;
        if (OBF16)
          ((u16*)Cv)[orow * (long)ldc + gc] = f2bf(v);
        else
          ((float*)Cv)[orow * (long)ldc + gc] = v;
      }
    }
  }
}

// ============================================================================
// gemm2<128,128,2,2>: 2-phase double-buffered GEMM (r9/r13-proven). For
// SMALL grids (~300 blocks: patch, wo, fc2).
// ============================================================================
template <int BM, int BN, int WM, int WN, bool BIAS, bool GELU, bool RES,
          bool OBF16, bool REMAP>
__global__ __launch_bounds__(WM * WN * 64, 2) void gemm2(
    const u16* __restrict__ A, int lda,
    const u16* __restrict__ Bm, int ldb,
    void* Cv, int ldc,
    const float* __restrict__ bias, const float* res, int ldres,
    int M, int N, int K, int tilesN) {
  constexpr int THREADS = WM * WN * 64;
  constexpr int TM = BM / WM, TN = BN / WN;
  constexpr int FM = TM / 16, FN = TN / 16;
  constexpr int APT = (BM * 8) / THREADS;
  constexpr int BPT = (BN * 8) / THREADS;
  constexpr int ABYTES = BM * 128;
  constexpr int BUF = ABYTES + BN * 128;
  __shared__ __align__(16) char smem[2 * BUF];

  const int t = threadIdx.x;
  const int l = t & 63;
  const int lr = l & 15, kb = (l >> 4) & 3;
  const int wid = t >> 6;
  const int wr = wid / WN, wc = wid % WN;

  const int nwg = gridDim.x;
  const int orig = blockIdx.x;
  const int q8 = nwg >> 3, r8 = nwg & 7;
  const int xcd = orig & 7, loc = orig >> 3;
  const int wg =
      (xcd < r8 ? xcd * (q8 + 1) : r8 * (q8 + 1) + (xcd - r8) * q8) + loc;
  const int tn = wg % tilesN, tm = wg / tilesN;
  const int m0 = tm * BM, n0 = tn * BN;
  const int Mm1 = M - 1, Nm1 = N - 1;

  const f32x4 zf = {0.f, 0.f, 0.f, 0.f};
  f32x4 acc[FM][FN];
#pragma unroll
  for (int fm = 0; fm < FM; ++fm)
#pragma unroll
    for (int fn = 0; fn < FN; ++fn) acc[fm][fn] = zf;

  auto stage = [&](int kt, int d) {
    const int k0 = kt << 6;
    char* base = smem + d * BUF;
#pragma unroll
    for (int p = 0; p < APT; ++p) {
      int idx = p * THREADS + t;
      int r = idx >> 3, cl = idx & 7;
      int rr = m0 + r;
      rr = rr > Mm1 ? Mm1 : rr;
      gload_lds16(A + (long)rr * lda + k0 + ((cl ^ (r & 7)) << 3),
                  base + ((p * THREADS + (t & ~63)) << 4));
    }
    char* bbase = base + ABYTES;
#pragma unroll
    for (int p = 0; p < BPT; ++p) {
      int idx = p * THREADS + t;
      int r = idx >> 3, cl = idx & 7;
      int rr = n0 + r;
      rr = rr > Nm1 ? Nm1 : rr;
      gload_lds16(Bm + (long)rr * ldb + k0 + ((cl ^ (r & 7)) << 3),
                  bbase + ((p * THREADS + (t & ~63)) << 4));
    }
  };

  const int nt = K >> 6;
  stage(0, 0);
  __syncthreads();

  for (int kt = 0; kt < nt; ++kt) {
    if (kt + 1 < nt) stage(kt + 1, (kt + 1) & 1);  // issue BEFORE compute
    const char* Ab = smem + (kt & 1) * BUF;
    const char* Bb = Ab + ABYTES;
#pragma unroll
    for (int kk = 0; kk < 2; ++kk) {
      const int ch = ((((kk << 2) | kb) ^ (lr & 7)) << 4);
      short8 af[FM], bf[FN];
#pragma unroll
      for (int fm = 0; fm < FM; ++fm)
        af[fm] = *(const short8*)(Ab + (wr * TM + fm * 16 + lr) * 128 + ch);
#pragma unroll
      for (int fn = 0; fn < FN; ++fn)
        bf[fn] = *(const short8*)(Bb + (wc * TN + fn * 16 + lr) * 128 + ch);
#pragma unroll
      for (int fm = 0; fm < FM; ++fm)
#pragma unroll
        for (int fn = 0; fn < FN; ++fn)
          acc[fm][fn] = __builtin_amdgcn_mfma_f32_16x16x32_bf16(af[fm], bf[fn],
                                                                acc[fm][fn], 0, 0, 0);
    }
    __syncthreads();
  }

#pragma unroll
  for (int fn = 0; fn < FN; ++fn) {
    const int gc = n0 + wc * TN + fn * 16 + lr;
    if (gc >= N) continue;
    const float bv = BIAS ? bias[gc] : 0.0f;
#pragma unroll
    for (int fm = 0; fm < FM; ++fm) {
#pragma unroll
      for (int j = 0; j < 4; ++j) {
        const int gr = m0 + wr * TM + fm * 16 + kb * 4 + j;
        if (gr >= M) continue;
        float v = acc[fm][fn][j] + bv;
        if (RES) v += res[(long)gr * ldres + gc];
        if (GELU) v = gelu_f(v);
        long orow = gr;
        if (REMAP) orow = (long)(gr / 196) * 197 + (gr % 196) + 1;
        if (OBF16)
          ((u16*)Cv)[orow * (long)ldc + gc] = f2bf(v);
        else
          ((float*)Cv)[orow * (long)ldc + gc] = v;
      }
    }
  }
}

// ============================================================================
// k_attn: fused attention for one (b, h). 256 thr / 4 waves. (r6-proven)
// ============================================================================
__global__ __launch_bounds__(256) void k_attn(const u16* __restrict__ qkv,
                                              u16* __restrict__ o) {
  __shared__ __align__(16) u16 Kb[208 * 72];
  __shared__ __align__(16) u16 Vt[64 * 232];
  __shared__ __align__(16) u16 Pl[4][16 * 232];

  const int t = threadIdx.x;
  const int z = blockIdx.x;  // b*12 + h
  const int b = z / 12, hh = z % 12;
  const long qbase = (long)b * SP * 2304 + hh * 64;

#pragma unroll
  for (int p = 0; p < 7; ++p) {
    int idx = p * 256 + t;  // 0..1791
    int row = idx >> 3, c = idx & 7;
    short8 kv = {0, 0, 0, 0, 0, 0, 0, 0};
    short8 vv = {0, 0, 0, 0, 0, 0, 0, 0};
    if (row < SP) {
      kv = *(const short8*)(qkv + qbase + 768 + (long)row * 2304 + c * 8);
      vv = *(const short8*)(qkv + qbase + 1536 + (long)row * 2304 + c * 8);
    }
    if (row < 208) *(short8*)(&Kb[row * 72 + c * 8]) = kv;
#pragma unroll
    for (int j = 0; j < 8; ++j) Vt[(c * 8 + j) * 232 + row] = ((const u16*)&vv)[j];
  }
  __syncthreads();

  const int l = t & 63, wid = t >> 6;
  const int lr = l & 15, kb = l >> 4;  // 0..3
  u16* Pw = Pl[wid];
  const f32x4 zf = {0.f, 0.f, 0.f, 0.f};

  for (int st = wid; st < 13; st += 4) {
    int qrow = st * 16 + lr;
    qrow = qrow > SP - 1 ? SP - 1 : qrow;
    short8 qf[2];
#pragma unroll
    for (int kk = 0; kk < 2; ++kk)
      qf[kk] = *(const short8*)(qkv + qbase + (long)qrow * 2304 + kk * 32 + kb * 8);

    f32x4 s[13];
#pragma unroll
    for (int nt = 0; nt < 13; ++nt) {
      s[nt] = zf;
#pragma unroll
      for (int kk = 0; kk < 2; ++kk) {
        short8 kf = *(const short8*)(&Kb[(nt * 16 + lr) * 72 + kk * 32 + kb * 8]);
        s[nt] = __builtin_amdgcn_mfma_f32_16x16x32_bf16(qf[kk], kf, s[nt], 0, 0, 0);
      }
    }

    float mx[4] = {-1e30f, -1e30f, -1e30f, -1e30f};
#pragma unroll
    for (int nt = 0; nt < 13; ++nt) {
      const bool pred = (nt < 12) | (lr < 5);
#pragma unroll
      for (int j = 0; j < 4; ++j) {
        float v = s[nt][j] * 0.125f;
        s[nt][j] = v;
        if (pred) mx[j] = fmaxf(mx[j], v);
      }
    }
#pragma unroll
    for (int o4 = 1; o4 < 16; o4 <<= 1)
#pragma unroll
      for (int j = 0; j < 4; ++j) mx[j] = fmaxf(mx[j], __shfl_xor(mx[j], o4));
    float sum[4] = {0.f, 0.f, 0.f, 0.f};
#pragma unroll
    for (int nt = 0; nt < 13; ++nt) {
      const bool pred = (nt < 12) | (lr < 5);
#pragma unroll
      for (int j = 0; j < 4; ++j) {
        float p = pred ? __expf(s[nt][j] - mx[j]) : 0.f;
        s[nt][j] = p;
        sum[j] += p;
      }
    }
#pragma unroll
    for (int o4 = 1; o4 < 16; o4 <<= 1)
#pragma unroll
      for (int j = 0; j < 4; ++j) sum[j] += __shfl_xor(sum[j], o4);
    float inv[4];
#pragma unroll
    for (int j = 0; j < 4; ++j) inv[j] = 1.0f / sum[j];

#pragma unroll
    for (int nt = 0; nt < 13; ++nt)
#pragma unroll
      for (int j = 0; j < 4; ++j)
        Pw[(kb * 4 + j) * 232 + nt * 16 + lr] = f2bf(s[nt][j] * inv[j]);
#pragma unroll
    for (int j = 0; j < 4; ++j) Pw[(kb * 4 + j) * 232 + 208 + lr] = 0;

    short8 pf[7];
#pragma unroll
    for (int kk = 0; kk < 7; ++kk)
      pf[kk] = *(const short8*)(&Pw[lr * 232 + kk * 32 + kb * 8]);
#pragma unroll
    for (int dt = 0; dt < 4; ++dt) {
      f32x4 oacc = zf;
#pragma unroll
      for (int kk = 0; kk < 7; ++kk) {
        short8 vf = *(const short8*)(&Vt[(dt * 16 + lr) * 232 + kk * 32 + kb * 8]);
        oacc = __builtin_amdgcn_mfma_f32_16x16x32_bf16(pf[kk], vf, oacc, 0, 0, 0);
      }
#pragma unroll
      for (int j = 0; j < 4; ++j) {
        int qr = st * 16 + kb * 4 + j;
        if (qr < SP)
          o[((long)b * SP + qr) * 768 + hh * 64 + dt * 16 + lr] = f2bf(oacc[j]);
      }
    }
  }
}

// ---- weight repack kernels ----
__global__ void k_wt64(const float* __restrict__ W, u16* __restrict__ out,
                       int sel) {
  __shared__ float tile[32][33];
  const int z = blockIdx.z;  // ly*12+hh
  const int ly = z / 12, hh = z % 12;
  const float* ip = W + (long)z * 768 * 64;
  u16* op = out + (long)ly * 2304 * 768 + ((long)sel * 768 + hh * 64) * 768;
  const int c0 = blockIdx.x * 32, r0 = blockIdx.y * 32;
  const int tx = threadIdx.x, ty = threadIdx.y;
#pragma unroll
  for (int i = 0; i < 4; ++i)
    tile[ty + i * 8][tx] = ip[(long)(r0 + ty + i * 8) * 64 + c0 + tx];
  __syncthreads();
#pragma unroll
  for (int i = 0; i < 4; ++i)
    op[(long)(c0 + ty + i * 8) * 768 + r0 + tx] = f2bf(tile[tx][ty + i * 8]);
}

__global__ void k_bqkv(const float* __restrict__ bq, const float* __restrict__ bk,
                       const float* __restrict__ bv, float* __restrict__ out) {
  int idx = blockIdx.x * 256 + threadIdx.x;
  if (idx >= 27648) return;
  int c = idx % 2304, ly = idx / 2304;
  int sel = c / 768, cc = c % 768;
  const float* b = sel == 0 ? bq : (sel == 1 ? bk : bv);
  out[idx] = b[ly * 768 + cc];
}

__global__ void k_transpose(const float* __restrict__ in, u16* __restrict__ out,
                            int R, int C) {
  __shared__ float tile[32][33];
  long zoff = (long)blockIdx.z * R * C;
  const float* ip = in + zoff;
  u16* op = out + zoff;
  int c0 = blockIdx.x * 32, r0 = blockIdx.y * 32;
  int tx = threadIdx.x, ty = threadIdx.y;
#pragma unroll
  for (int i = 0; i < 4; ++i)
    tile[ty + i * 8][tx] = ip[(long)(r0 + ty + i * 8) * C + c0 + tx];
  __syncthreads();
#pragma unroll
  for (int i = 0; i < 4; ++i)
    op[(long)(c0 + ty + i * 8) * R + r0 + tx] = f2bf(tile[tx][ty + i * 8]);
}

// ---- activation-side kernels ----
__global__ void k_patchify(const float* __restrict__ x, u16* __restrict__ out) {
  long idx = (long)blockIdx.x * 256 + threadIdx.x;
  int f = (int)(idx % 768);
  long rp = idx / 768;
  int p = (int)(rp % 196), b = (int)(rp / 196);
  int gy = p / 14, gx = p % 14;
  int c = f >> 8, rem = f & 255;
  int i = rem >> 4, j = rem & 15;
  out[idx] = f2bf(x[(((long)b * 3 + c) * 224 + gy * 16 + i) * 224 + gx * 16 + j]);
}

// h[b,s,:] += pos[s,:] (+cls at s=0), float4-vectorized
__global__ void k_add_pos(float* h, const float* __restrict__ cls,
                          const float* __restrict__ pos) {
  long idx = (long)blockIdx.x * 256 + threadIdx.x;  // 6304*192
  int d4 = (int)(idx % 192);
  long rs = idx / 192;
  int s = (int)(rs % 197);
  float4* hp = (float4*)h;
  const float4* pp = (const float4*)pos;
  if (s == 0) {
    const float4* cp = (const float4*)cls;
    float4 v = cp[d4], w = pp[d4];
    v.x += w.x; v.y += w.y; v.z += w.z; v.w += w.w;
    hp[idx] = v;
  } else {
    float4 v = hp[idx], w = pp[(long)s * 192 + d4];
    v.x += w.x; v.y += w.y; v.z += w.z; v.w += w.w;
    hp[idx] = v;
  }
}

__global__ __launch_bounds__(256) void k_ln(const float* __restrict__ in,
                                            const float* __restrict__ g,
                                            const float* __restrict__ b,
                                            u16* __restrict__ out, int rows) {
  int w = threadIdx.x >> 6, l = threadIdx.x & 63;
  int row = blockIdx.x * 4 + w;
  if (row >= rows) return;
  const float4* ip = (const float4*)(in + (long)row * 768);
  float4 v[3];
  float s = 0.f, sq = 0.f;
#pragma unroll
  for (int i = 0; i < 3; ++i) {
    v[i] = ip[i * 64 + l];
    s += v[i].x + v[i].y + v[i].z + v[i].w;
    sq += v[i].x * v[i].x + v[i].y * v[i].y + v[i].z * v[i].z + v[i].w * v[i].w;
  }
#pragma unroll
  for (int o = 1; o < 64; o <<= 1) {
    s += __shfl_xor(s, o);
    sq += __shfl_xor(sq, o);
  }
  const float m = s * (1.f / 768.f);
  const float rs = rsqrtf(sq * (1.f / 768.f) - m * m + 1e-5f);
  ushort4* op = (ushort4*)(out + (long)row * 768);
#pragma unroll
  for (int i = 0; i < 3; ++i) {
    int c4 = (i * 64 + l) * 4;
    float4 gv = *(const float4*)(g + c4);
    float4 bv = *(const float4*)(b + c4);
    ushort4 o4;
    o4.x = f2bf((v[i].x - m) * rs * gv.x + bv.x);
    o4.y = f2bf((v[i].y - m) * rs * gv.y + bv.y);
    o4.z = f2bf((v[i].z - m) * rs * gv.z + bv.z);
    o4.w = f2bf((v[i].w - m) * rs * gv.w + bv.w);
    op[i * 64 + l] = o4;
  }
}

// ---- head (f32) ----
__global__ void k_head_ln(const float* __restrict__ h, const float* __restrict__ g,
                          const float* __restrict__ b, float* __restrict__ out) {
  const int bb = blockIdx.x, l = threadIdx.x;
  const float4* ip = (const float4*)(h + (long)bb * 197 * 768);
  float4 v[3];
  float s = 0.f, sq = 0.f;
#pragma unroll
  for (int i = 0; i < 3; ++i) {
    v[i] = ip[i * 64 + l];
    s += v[i].x + v[i].y + v[i].z + v[i].w;
    sq += v[i].x * v[i].x + v[i].y * v[i].y + v[i].z * v[i].z + v[i].w * v[i].w;
  }
#pragma unroll
  for (int o = 1; o < 64; o <<= 1) {
    s += __shfl_xor(s, o);
    sq += __shfl_xor(sq, o);
  }
  const float m = s * (1.f / 768.f);
  const float rs = rsqrtf(sq * (1.f / 768.f) - m * m + 1e-5f);
  float4* op = (float4*)(out + bb * 768);
#pragma unroll
  for (int i = 0; i < 3; ++i) {
    int c4 = (i * 64 + l) * 4;
    float4 gv = *(const float4*)(g + c4);
    float4 bv = *(const float4*)(b + c4);
    float4 o4;
    o4.x = (v[i].x - m) * rs * gv.x + bv.x;
    o4.y = (v[i].y - m) * rs * gv.y + bv.y;
    o4.z = (v[i].z - m) * rs * gv.z + bv.z;
    o4.w = (v[i].w - m) * rs * gv.w + bv.w;
    op[i * 64 + l] = o4;
  }
}

template <bool GELU>
__global__ __launch_bounds__(256) void k_head_gemm(
    const float* __restrict__ in, const float* __restrict__ W,
    const float* __restrict__ bias, float* __restrict__ out, int K, int N) {
  __shared__ float partial[4][64];
  const int b = blockIdx.y;
  const int cl = threadIdx.x & 63;
  const int c = blockIdx.x * 64 + cl;
  const int kp = threadIdx.x >> 6;
  const int kc = K >> 2;
  float s = 0.f;
  if (c < N) {
    const float* ip = in + (long)b * K + kp * kc;
    const float* wp = W + (long)(kp * kc) * N + c;
    for (int k = 0; k < kc; ++k) s = fmaf(ip[k], wp[(long)k * N], s);
  }
  partial[kp][cl] = s;
  __syncthreads();
  if (kp == 0 && c < N) {
    float v = partial[0][cl] + partial[1][cl] + partial[2][cl] + partial[3][cl] +
              bias[c];
    if (GELU) v = gelu_f(v);
    out[(long)b * N + c] = v;
  }
}

extern "C" void kernel_launch(void* const* d_in, const int* in_sizes, int n_in,
                              void* d_out, int out_size, void* d_ws, size_t ws_size,
                              hipStream_t stream) {
  (void)in_sizes; (void)n_in; (void)out_size;
  if ((long)ws_size < WS_NEEDED) return;

  const float* x = (const float*)d_in[0];
  const float* Wp = (const float*)d_in[1];
  const float* bp = (const float*)d_in[2];
  const float* cls = (const float*)d_in[3];
  const float* pos = (const float*)d_in[4];
  const float* ln1g = (const float*)d_in[5];
  const float* ln1b = (const float*)d_in[6];
  const float* Wq = (const float*)d_in[7];
  const float* bq = (const float*)d_in[8];
  const float* Wk = (const float*)d_in[9];
  const float* bk = (const float*)d_in[10];
  const float* Wv = (const float*)d_in[11];
  const float* bv = (const float*)d_in[12];
  const float* Wo = (const float*)d_in[13];
  const float* bo = (const float*)d_in[14];
  const float* ln2g = (const float*)d_in[15];
  const float* ln2b = (const float*)d_in[16];
  const float* W1 = (const float*)d_in[17];
  const float* b1 = (const float*)d_in[18];
  const float* W2 = (const float*)d_in[19];
  const float* b2 = (const float*)d_in[20];
  const float* hlng = (const float*)d_in[21];
  const float* hlnb = (const float*)d_in[22];
  const float* hW1 = (const float*)d_in[23];
  const float* hb1 = (const float*)d_in[24];
  const float* hW2 = (const float*)d_in[25];
  const float* hb2 = (const float*)d_in[26];

  char* ws = (char*)d_ws;
  u16* wqkvt = (u16*)(ws + OFF_WQKVT);
  u16* wot = (u16*)(ws + OFF_WOT);
  u16* w1t = (u16*)(ws + OFF_W1T);
  u16* w2t = (u16*)(ws + OFF_W2T);
  u16* wpt = (u16*)(ws + OFF_WPT);
  float* bqkv = (float*)(ws + OFF_BQKV);
  float* h = (float*)(ws + OFF_H);
  u16* xn = (u16*)(ws + OFF_XN);
  u16* qkv = (u16*)(ws + OFF_QKV);
  u16* pbuf = qkv;
  u16* m1 = (u16*)(ws + OFF_PM1);
  float* cn = (float*)(ws + OFF_CN);
  float* t1 = (float*)(ws + OFF_T1);

  // ---- per-call weight repack ----
  k_wt64<<<dim3(2, 24, 144), dim3(32, 8), 0, stream>>>(Wq, wqkvt, 0);
  k_wt64<<<dim3(2, 24, 144), dim3(32, 8), 0, stream>>>(Wk, wqkvt, 1);
  k_wt64<<<dim3(2, 24, 144), dim3(32, 8), 0, stream>>>(Wv, wqkvt, 2);
  k_bqkv<<<108, 256, 0, stream>>>(bq, bk, bv, bqkv);
  k_transpose<<<dim3(24, 24, 12), dim3(32, 8), 0, stream>>>(Wo, wot, 768, 768);
  k_transpose<<<dim3(96, 24, 12), dim3(32, 8), 0, stream>>>(W1, w1t, 768, 3072);
  k_transpose<<<dim3(24, 96, 12), dim3(32, 8), 0, stream>>>(W2, w2t, 3072, 768);
  k_transpose<<<dim3(24, 24, 1), dim3(32, 8), 0, stream>>>(Wp, wpt, 768, 768);

  // ---- patch embed ----
  k_patchify<<<18816, 256, 0, stream>>>(x, pbuf);
  gemm2<128, 128, 2, 2, true, false, false, false, true><<<294, 256, 0, stream>>>(
      pbuf, 768, wpt, 768, h, 768, bp, nullptr, 0, 6272, 768, 768, 6);
  k_add_pos<<<4728, 256, 0, stream>>>(h, cls, pos);

  // ---- transformer layers ----
  for (int ly = 0; ly < 12; ++ly) {
    k_ln<<<1576, 256, 0, stream>>>(h, ln1g + ly * 768, ln1b + ly * 768, xn, NTOK);
    gemm_k<true, false, false, true, false><<<900, 256, 0, stream>>>(
        xn, 768, wqkvt + (long)ly * 2304 * 768, 768, qkv, 2304,
        bqkv + ly * 2304, nullptr, 0, NTOK, 2304, 768, 18);
    // fused attention: qkv -> xn (o laid out [b,s,h*64+dh])
    k_attn<<<384, 256, 0, stream>>>(qkv, xn);
    // h = o @ Wo + bo + h  (small grid -> gemm2)
    gemm2<128, 128, 2, 2, true, false, true, false, false><<<300, 256, 0, stream>>>(
        xn, 768, wot + (long)ly * 768 * 768, 768, h, 768,
        bo + ly * 768, h, 768, NTOK, 768, 768, 6);
    k_ln<<<1576, 256, 0, stream>>>(h, ln2g + ly * 768, ln2b + ly * 768, xn, NTOK);
    gemm_w<true, true, false, true, false><<<600, 512, 0, stream>>>(
        xn, 768, w1t + (long)ly * 3072 * 768, 768, m1, 3072,
        b1 + ly * 3072, nullptr, 0, NTOK, 3072, 768, 24);
    gemm2<128, 128, 2, 2, true, false, true, false, false><<<300, 256, 0, stream>>>(
        m1, 3072, w2t + (long)ly * 768 * 3072, 3072, h, 768,
        b2 + ly * 768, h, 768, NTOK, 768, 3072, 6);
  }

  // ---- head ----
  k_head_ln<<<32, 64, 0, stream>>>(h, hlng, hlnb, cn);
  k_head_gemm<true><<<dim3(12, 32), 256, 0, stream>>>(cn, hW1, hb1, t1, 768, 768);
  k_head_gemm<false><<<dim3(16, 32), 256, 0, stream>>>(t1, hW2, hb2, (float*)d_out,
                                                       768, 1000);
}

// Round 16
// 3245.689 us; speedup vs baseline: 1.0133x; 1.0133x over previous
//
#include <hip/hip_runtime.h>

typedef unsigned short u16;
typedef __attribute__((ext_vector_type(8))) short short8;
typedef __attribute__((ext_vector_type(4))) float f32x4;

#define NTOK 6304   // 32*197
#define SP 197

// ---- workspace offsets (bytes) ----
#define OFF_WQKVT 0L
#define OFF_WOT   42467328L
#define OFF_W1T   56623104L
#define OFF_W2T   113246208L
#define OFF_WPT   169869312L
#define OFF_BQKV  171048960L
#define OFF_H     171159552L
#define OFF_XN    190525440L
#define OFF_QKV   200208384L
#define OFF_SC    229257216L
#define OFF_PM1   288867840L
#define OFF_VT    327599616L
#define OFF_CN    340182528L
#define OFF_T1    340280832L
#define WS_NEEDED 340379136L

__device__ __forceinline__ u16 f2bf(float x) {
  unsigned int u = __float_as_uint(x);
  u += 0x7fffu + ((u >> 16) & 1u);
  return (u16)(u >> 16);
}

__device__ __forceinline__ float gelu_f(float x) {
  return 0.5f * x * (1.0f + erff(x * 0.70710678118654752f));
}

__device__ __forceinline__ void gload_lds16(const void* g, void* l) {
  __builtin_amdgcn_global_load_lds(
      (const __attribute__((address_space(1))) unsigned int*)g,
      (__attribute__((address_space(3))) unsigned int*)l, 16, 0, 0);
}

// ============================================================================
// gemm_k: m97-structure 128^2 single-buffer GEMM (r8/r13-proven) + bijective
// XCD swizzle, tn-fastest. For large grids (qkv@900, fc1@1200).
// ============================================================================
template <bool BIAS, bool GELU, bool RES, bool OBF16, bool REMAP>
__global__ __launch_bounds__(256, 3) void gemm_k(
    const u16* __restrict__ A, int lda,
    const u16* __restrict__ Bm, int ldb,
    void* Cv, int ldc,
    const float* __restrict__ bias, const float* res, int ldres,
    int M, int N, int K, int tilesN) {
  __shared__ float4 smemv[2048];
  char* smem = (char*)smemv;

  const int t = threadIdx.x;
  const int nwg = gridDim.x;
  const int orig = blockIdx.x;
  const int q8 = nwg >> 3, r8 = nwg & 7;
  const int xcd = orig & 7, loc = orig >> 3;
  const int wg =
      (xcd < r8 ? xcd * (q8 + 1) : r8 * (q8 + 1) + (xcd - r8) * q8) + loc;
  const int tn = wg % tilesN, tm = wg / tilesN;
  const int m0 = tm * 128, n0 = tn * 128;
  const int l = t & 63;
  const int lr = l & 15, kb = l >> 4;
  const int wr = (t >> 7) & 1, wc = (t >> 6) & 1;

  const f32x4 zf = {0.f, 0.f, 0.f, 0.f};
  f32x4 acc[4][4];
#pragma unroll
  for (int m = 0; m < 4; ++m)
#pragma unroll
    for (int n = 0; n < 4; ++n) acc[m][n] = zf;

  auto stage = [&](const u16* src, int ld, int row0, int maxrow, int k0,
                   char* ldsbase) {
#pragma unroll
    for (int p = 0; p < 4; ++p) {
      int idx = p * 256 + t;
      int r = idx >> 3;
      int cl = idx & 7;
      int cg = cl ^ (r & 7);
      int rr = row0 + r;
      rr = rr > maxrow ? maxrow : rr;
      gload_lds16(src + (long)rr * ld + k0 + cg * 8,
                  ldsbase + (long)(p * 256 + (t & ~63)) * 16);
    }
  };

  const int KT = K >> 6;
  for (int kt = 0; kt < KT; ++kt) {
    stage(A, lda, m0, M - 1, kt * 64, smem);
    stage(Bm, ldb, n0, N - 1, kt * 64, smem + 16384);
    __syncthreads();
    const char* Ab = smem;
    const char* Bb = smem + 16384;
#pragma unroll
    for (int kk = 0; kk < 2; ++kk) {
      const int cla = ((kk << 2) + kb) ^ (lr & 7);
      short8 af[4], bfv[4];
#pragma unroll
      for (int m = 0; m < 4; ++m)
        af[m] = *(const short8*)(Ab + ((wr * 64 + m * 16 + lr) * 128 + cla * 16));
#pragma unroll
      for (int n = 0; n < 4; ++n)
        bfv[n] = *(const short8*)(Bb + ((wc * 64 + n * 16 + lr) * 128 + cla * 16));
#pragma unroll
      for (int m = 0; m < 4; ++m)
#pragma unroll
        for (int n = 0; n < 4; ++n)
          acc[m][n] = __builtin_amdgcn_mfma_f32_16x16x32_bf16(af[m], bfv[n],
                                                              acc[m][n], 0, 0, 0);
    }
    __syncthreads();
  }

#pragma unroll
  for (int n = 0; n < 4; ++n) {
    const int gc = n0 + wc * 64 + n * 16 + lr;
    if (gc >= N) continue;
    const float bv = BIAS ? bias[gc] : 0.0f;
#pragma unroll
    for (int m = 0; m < 4; ++m) {
#pragma unroll
      for (int j = 0; j < 4; ++j) {
        const int gr = m0 + wr * 64 + m * 16 + kb * 4 + j;
        if (gr >= M) continue;
        float v = acc[m][n][j] + bv;
        if (RES) v += res[(long)gr * ldres + gc];
        if (GELU) v = gelu_f(v);
        long orow = gr;
        if (REMAP) orow = (long)(gr / 196) * 197 + (gr % 196) + 1;
        if (OBF16)
          ((u16*)Cv)[orow * (long)ldc + gc] = f2bf(v);
        else
          ((float*)Cv)[orow * (long)ldc + gc] = v;
      }
    }
  }
}

// ============================================================================
// gemm2<128,128,2,2>: 2-phase double-buffered GEMM (r9/r13-proven). For
// SMALL grids (~300 blocks: patch, wo, fc2) — in-block prefetch pays there.
// ============================================================================
template <int BM, int BN, int WM, int WN, bool BIAS, bool GELU, bool RES,
          bool OBF16, bool REMAP>
__global__ __launch_bounds__(WM * WN * 64, 2) void gemm2(
    const u16* __restrict__ A, int lda,
    const u16* __restrict__ Bm, int ldb,
    void* Cv, int ldc,
    const float* __restrict__ bias, const float* res, int ldres,
    int M, int N, int K, int tilesN) {
  constexpr int THREADS = WM * WN * 64;
  constexpr int TM = BM / WM, TN = BN / WN;
  constexpr int FM = TM / 16, FN = TN / 16;
  constexpr int APT = (BM * 8) / THREADS;
  constexpr int BPT = (BN * 8) / THREADS;
  constexpr int ABYTES = BM * 128;
  constexpr int BUF = ABYTES + BN * 128;
  __shared__ __align__(16) char smem[2 * BUF];

  const int t = threadIdx.x;
  const int l = t & 63;
  const int lr = l & 15, kb = (l >> 4) & 3;
  const int wid = t >> 6;
  const int wr = wid / WN, wc = wid % WN;

  const int nwg = gridDim.x;
  const int orig = blockIdx.x;
  const int q8 = nwg >> 3, r8 = nwg & 7;
  const int xcd = orig & 7, loc = orig >> 3;
  const int wg =
      (xcd < r8 ? xcd * (q8 + 1) : r8 * (q8 + 1) + (xcd - r8) * q8) + loc;
  const int tn = wg % tilesN, tm = wg / tilesN;
  const int m0 = tm * BM, n0 = tn * BN;
  const int Mm1 = M - 1, Nm1 = N - 1;

  const f32x4 zf = {0.f, 0.f, 0.f, 0.f};
  f32x4 acc[FM][FN];
#pragma unroll
  for (int fm = 0; fm < FM; ++fm)
#pragma unroll
    for (int fn = 0; fn < FN; ++fn) acc[fm][fn] = zf;

  auto stage = [&](int kt, int d) {
    const int k0 = kt << 6;
    char* base = smem + d * BUF;
#pragma unroll
    for (int p = 0; p < APT; ++p) {
      int idx = p * THREADS + t;
      int r = idx >> 3, cl = idx & 7;
      int rr = m0 + r;
      rr = rr > Mm1 ? Mm1 : rr;
      gload_lds16(A + (long)rr * lda + k0 + ((cl ^ (r & 7)) << 3),
                  base + ((p * THREADS + (t & ~63)) << 4));
    }
    char* bbase = base + ABYTES;
#pragma unroll
    for (int p = 0; p < BPT; ++p) {
      int idx = p * THREADS + t;
      int r = idx >> 3, cl = idx & 7;
      int rr = n0 + r;
      rr = rr > Nm1 ? Nm1 : rr;
      gload_lds16(Bm + (long)rr * ldb + k0 + ((cl ^ (r & 7)) << 3),
                  bbase + ((p * THREADS + (t & ~63)) << 4));
    }
  };

  const int nt = K >> 6;
  stage(0, 0);
  __syncthreads();

  for (int kt = 0; kt < nt; ++kt) {
    if (kt + 1 < nt) stage(kt + 1, (kt + 1) & 1);  // issue BEFORE compute
    const char* Ab = smem + (kt & 1) * BUF;
    const char* Bb = Ab + ABYTES;
#pragma unroll
    for (int kk = 0; kk < 2; ++kk) {
      const int ch = ((((kk << 2) | kb) ^ (lr & 7)) << 4);
      short8 af[FM], bf[FN];
#pragma unroll
      for (int fm = 0; fm < FM; ++fm)
        af[fm] = *(const short8*)(Ab + (wr * TM + fm * 16 + lr) * 128 + ch);
#pragma unroll
      for (int fn = 0; fn < FN; ++fn)
        bf[fn] = *(const short8*)(Bb + (wc * TN + fn * 16 + lr) * 128 + ch);
#pragma unroll
      for (int fm = 0; fm < FM; ++fm)
#pragma unroll
        for (int fn = 0; fn < FN; ++fn)
          acc[fm][fn] = __builtin_amdgcn_mfma_f32_16x16x32_bf16(af[fm], bf[fn],
                                                                acc[fm][fn], 0, 0, 0);
    }
    __syncthreads();
  }

#pragma unroll
  for (int fn = 0; fn < FN; ++fn) {
    const int gc = n0 + wc * TN + fn * 16 + lr;
    if (gc >= N) continue;
    const float bv = BIAS ? bias[gc] : 0.0f;
#pragma unroll
    for (int fm = 0; fm < FM; ++fm) {
#pragma unroll
      for (int j = 0; j < 4; ++j) {
        const int gr = m0 + wr * TM + fm * 16 + kb * 4 + j;
        if (gr >= M) continue;
        float v = acc[fm][fn][j] + bv;
        if (RES) v += res[(long)gr * ldres + gc];
        if (GELU) v = gelu_f(v);
        long orow = gr;
        if (REMAP) orow = (long)(gr / 196) * 197 + (gr % 196) + 1;
        if (OBF16)
          ((u16*)Cv)[orow * (long)ldc + gc] = f2bf(v);
        else
          ((float*)Cv)[orow * (long)ldc + gc] = v;
      }
    }
  }
}

// ============================================================================
// k_attn: fused attention for one (b, h). 256 thr / 4 waves. (r6-proven)
// FIX (r16): the Vt transpose-scatter write was 8-way bank-conflicted
// (stride 232 u16: c-lanes 928 dwords apart = bank-0 aligned; 2.4M conflict
// cycles/dispatch in r15 counters). New Vt: stride 256 u16, XOR chunk
// swizzle s(dh)=((dh>>3)^dh)&7 — write colliders get 8 distinct chunks,
// reads stay 16B-aligned b128 with ~2-way aliasing (free, m136). Bijective:
// logical chunk c stored at c^s, read back at c^s.
// ============================================================================
__global__ __launch_bounds__(256) void k_attn(const u16* __restrict__ qkv,
                                              u16* __restrict__ o) {
  __shared__ __align__(16) u16 Kb[208 * 72];
  __shared__ __align__(16) u16 Vt[64 * 256];
  __shared__ __align__(16) u16 Pl[4][16 * 232];

  const int t = threadIdx.x;
  const int z = blockIdx.x;  // b*12 + h
  const int b = z / 12, hh = z % 12;
  const long qbase = (long)b * SP * 2304 + hh * 64;

#pragma unroll
  for (int p = 0; p < 7; ++p) {
    int idx = p * 256 + t;  // 0..1791
    int row = idx >> 3, c = idx & 7;
    short8 kv = {0, 0, 0, 0, 0, 0, 0, 0};
    short8 vv = {0, 0, 0, 0, 0, 0, 0, 0};
    if (row < SP) {
      kv = *(const short8*)(qkv + qbase + 768 + (long)row * 2304 + c * 8);
      vv = *(const short8*)(qkv + qbase + 1536 + (long)row * 2304 + c * 8);
    }
    if (row < 208) *(short8*)(&Kb[row * 72 + c * 8]) = kv;
#pragma unroll
    for (int j = 0; j < 8; ++j) {
      const int dh = c * 8 + j;
      const int s = ((dh >> 3) ^ dh) & 7;  // = (c ^ j) & 7
      Vt[dh * 256 + ((((row >> 3) ^ s)) << 3) + (row & 7)] = ((const u16*)&vv)[j];
    }
  }
  __syncthreads();

  const int l = t & 63, wid = t >> 6;
  const int lr = l & 15, kb = l >> 4;  // 0..3
  u16* Pw = Pl[wid];
  const f32x4 zf = {0.f, 0.f, 0.f, 0.f};

  for (int st = wid; st < 13; st += 4) {
    int qrow = st * 16 + lr;
    qrow = qrow > SP - 1 ? SP - 1 : qrow;
    short8 qf[2];
#pragma unroll
    for (int kk = 0; kk < 2; ++kk)
      qf[kk] = *(const short8*)(qkv + qbase + (long)qrow * 2304 + kk * 32 + kb * 8);

    f32x4 s[13];
#pragma unroll
    for (int nt = 0; nt < 13; ++nt) {
      s[nt] = zf;
#pragma unroll
      for (int kk = 0; kk < 2; ++kk) {
        short8 kf = *(const short8*)(&Kb[(nt * 16 + lr) * 72 + kk * 32 + kb * 8]);
        s[nt] = __builtin_amdgcn_mfma_f32_16x16x32_bf16(qf[kk], kf, s[nt], 0, 0, 0);
      }
    }

    float mx[4] = {-1e30f, -1e30f, -1e30f, -1e30f};
#pragma unroll
    for (int nt = 0; nt < 13; ++nt) {
      const bool pred = (nt < 12) | (lr < 5);
#pragma unroll
      for (int j = 0; j < 4; ++j) {
        float v = s[nt][j] * 0.125f;
        s[nt][j] = v;
        if (pred) mx[j] = fmaxf(mx[j], v);
      }
    }
#pragma unroll
    for (int o4 = 1; o4 < 16; o4 <<= 1)
#pragma unroll
      for (int j = 0; j < 4; ++j) mx[j] = fmaxf(mx[j], __shfl_xor(mx[j], o4));
    float sum[4] = {0.f, 0.f, 0.f, 0.f};
#pragma unroll
    for (int nt = 0; nt < 13; ++nt) {
      const bool pred = (nt < 12) | (lr < 5);
#pragma unroll
      for (int j = 0; j < 4; ++j) {
        float p = pred ? __expf(s[nt][j] - mx[j]) : 0.f;
        s[nt][j] = p;
        sum[j] += p;
      }
    }
#pragma unroll
    for (int o4 = 1; o4 < 16; o4 <<= 1)
#pragma unroll
      for (int j = 0; j < 4; ++j) sum[j] += __shfl_xor(sum[j], o4);
    float inv[4];
#pragma unroll
    for (int j = 0; j < 4; ++j) inv[j] = 1.0f / sum[j];

#pragma unroll
    for (int nt = 0; nt < 13; ++nt)
#pragma unroll
      for (int j = 0; j < 4; ++j)
        Pw[(kb * 4 + j) * 232 + nt * 16 + lr] = f2bf(s[nt][j] * inv[j]);
#pragma unroll
    for (int j = 0; j < 4; ++j) Pw[(kb * 4 + j) * 232 + 208 + lr] = 0;

    short8 pf[7];
#pragma unroll
    for (int kk = 0; kk < 7; ++kk)
      pf[kk] = *(const short8*)(&Pw[lr * 232 + kk * 32 + kb * 8]);
#pragma unroll
    for (int dt = 0; dt < 4; ++dt) {
      f32x4 oacc = zf;
      const int dh_r = dt * 16 + lr;
      const int sr = ((dh_r >> 3) ^ dh_r) & 7;
#pragma unroll
      for (int kk = 0; kk < 7; ++kk) {
        short8 vf = *(const short8*)(
            &Vt[dh_r * 256 + (((kk * 4 + kb) ^ sr) << 3)]);
        oacc = __builtin_amdgcn_mfma_f32_16x16x32_bf16(pf[kk], vf, oacc, 0, 0, 0);
      }
#pragma unroll
      for (int j = 0; j < 4; ++j) {
        int qr = st * 16 + kb * 4 + j;
        if (qr < SP)
          o[((long)b * SP + qr) * 768 + hh * 64 + dt * 16 + lr] = f2bf(oacc[j]);
      }
    }
  }
}

// ---- weight repack kernels ----
__global__ void k_wt64(const float* __restrict__ W, u16* __restrict__ out,
                       int sel) {
  __shared__ float tile[32][33];
  const int z = blockIdx.z;  // ly*12+hh
  const int ly = z / 12, hh = z % 12;
  const float* ip = W + (long)z * 768 * 64;
  u16* op = out + (long)ly * 2304 * 768 + ((long)sel * 768 + hh * 64) * 768;
  const int c0 = blockIdx.x * 32, r0 = blockIdx.y * 32;
  const int tx = threadIdx.x, ty = threadIdx.y;
#pragma unroll
  for (int i = 0; i < 4; ++i)
    tile[ty + i * 8][tx] = ip[(long)(r0 + ty + i * 8) * 64 + c0 + tx];
  __syncthreads();
#pragma unroll
  for (int i = 0; i < 4; ++i)
    op[(long)(c0 + ty + i * 8) * 768 + r0 + tx] = f2bf(tile[tx][ty + i * 8]);
}

__global__ void k_bqkv(const float* __restrict__ bq, const float* __restrict__ bk,
                       const float* __restrict__ bv, float* __restrict__ out) {
  int idx = blockIdx.x * 256 + threadIdx.x;
  if (idx >= 27648) return;
  int c = idx % 2304, ly = idx / 2304;
  int sel = c / 768, cc = c % 768;
  const float* b = sel == 0 ? bq : (sel == 1 ? bk : bv);
  out[idx] = b[ly * 768 + cc];
}

__global__ void k_transpose(const float* __restrict__ in, u16* __restrict__ out,
                            int R, int C) {
  __shared__ float tile[32][33];
  long zoff = (long)blockIdx.z * R * C;
  const float* ip = in + zoff;
  u16* op = out + zoff;
  int c0 = blockIdx.x * 32, r0 = blockIdx.y * 32;
  int tx = threadIdx.x, ty = threadIdx.y;
#pragma unroll
  for (int i = 0; i < 4; ++i)
    tile[ty + i * 8][tx] = ip[(long)(r0 + ty + i * 8) * C + c0 + tx];
  __syncthreads();
#pragma unroll
  for (int i = 0; i < 4; ++i)
    op[(long)(c0 + ty + i * 8) * R + r0 + tx] = f2bf(tile[tx][ty + i * 8]);
}

// ---- activation-side kernels ----
__global__ void k_patchify(const float* __restrict__ x, u16* __restrict__ out) {
  long idx = (long)blockIdx.x * 256 + threadIdx.x;
  int f = (int)(idx % 768);
  long rp = idx / 768;
  int p = (int)(rp % 196), b = (int)(rp / 196);
  int gy = p / 14, gx = p % 14;
  int c = f >> 8, rem = f & 255;
  int i = rem >> 4, j = rem & 15;
  out[idx] = f2bf(x[(((long)b * 3 + c) * 224 + gy * 16 + i) * 224 + gx * 16 + j]);
}

// h[b,s,:] += pos[s,:] (+cls at s=0), float4-vectorized
__global__ void k_add_pos(float* h, const float* __restrict__ cls,
                          const float* __restrict__ pos) {
  long idx = (long)blockIdx.x * 256 + threadIdx.x;  // 6304*192
  int d4 = (int)(idx % 192);
  long rs = idx / 192;
  int s = (int)(rs % 197);
  float4* hp = (float4*)h;
  const float4* pp = (const float4*)pos;
  if (s == 0) {
    const float4* cp = (const float4*)cls;
    float4 v = cp[d4], w = pp[d4];
    v.x += w.x; v.y += w.y; v.z += w.z; v.w += w.w;
    hp[idx] = v;
  } else {
    float4 v = hp[idx], w = pp[(long)s * 192 + d4];
    v.x += w.x; v.y += w.y; v.z += w.z; v.w += w.w;
    hp[idx] = v;
  }
}

__global__ __launch_bounds__(256) void k_ln(const float* __restrict__ in,
                                            const float* __restrict__ g,
                                            const float* __restrict__ b,
                                            u16* __restrict__ out, int rows) {
  int w = threadIdx.x >> 6, l = threadIdx.x & 63;
  int row = blockIdx.x * 4 + w;
  if (row >= rows) return;
  const float4* ip = (const float4*)(in + (long)row * 768);
  float4 v[3];
  float s = 0.f, sq = 0.f;
#pragma unroll
  for (int i = 0; i < 3; ++i) {
    v[i] = ip[i * 64 + l];
    s += v[i].x + v[i].y + v[i].z + v[i].w;
    sq += v[i].x * v[i].x + v[i].y * v[i].y + v[i].z * v[i].z + v[i].w * v[i].w;
  }
#pragma unroll
  for (int o = 1; o < 64; o <<= 1) {
    s += __shfl_xor(s, o);
    sq += __shfl_xor(sq, o);
  }
  const float m = s * (1.f / 768.f);
  const float rs = rsqrtf(sq * (1.f / 768.f) - m * m + 1e-5f);
  ushort4* op = (ushort4*)(out + (long)row * 768);
#pragma unroll
  for (int i = 0; i < 3; ++i) {
    int c4 = (i * 64 + l) * 4;
    float4 gv = *(const float4*)(g + c4);
    float4 bv = *(const float4*)(b + c4);
    ushort4 o4;
    o4.x = f2bf((v[i].x - m) * rs * gv.x + bv.x);
    o4.y = f2bf((v[i].y - m) * rs * gv.y + bv.y);
    o4.z = f2bf((v[i].z - m) * rs * gv.z + bv.z);
    o4.w = f2bf((v[i].w - m) * rs * gv.w + bv.w);
    op[i * 64 + l] = o4;
  }
}

// ---- head (f32) ----
__global__ void k_head_ln(const float* __restrict__ h, const float* __restrict__ g,
                          const float* __restrict__ b, float* __restrict__ out) {
  const int bb = blockIdx.x, l = threadIdx.x;
  const float4* ip = (const float4*)(h + (long)bb * 197 * 768);
  float4 v[3];
  float s = 0.f, sq = 0.f;
#pragma unroll
  for (int i = 0; i < 3; ++i) {
    v[i] = ip[i * 64 + l];
    s += v[i].x + v[i].y + v[i].z + v[i].w;
    sq += v[i].x * v[i].x + v[i].y * v[i].y + v[i].z * v[i].z + v[i].w * v[i].w;
  }
#pragma unroll
  for (int o = 1; o < 64; o <<= 1) {
    s += __shfl_xor(s, o);
    sq += __shfl_xor(sq, o);
  }
  const float m = s * (1.f / 768.f);
  const float rs = rsqrtf(sq * (1.f / 768.f) - m * m + 1e-5f);
  float4* op = (float4*)(out + bb * 768);
#pragma unroll
  for (int i = 0; i < 3; ++i) {
    int c4 = (i * 64 + l) * 4;
    float4 gv = *(const float4*)(g + c4);
    float4 bv = *(const float4*)(b + c4);
    float4 o4;
    o4.x = (v[i].x - m) * rs * gv.x + bv.x;
    o4.y = (v[i].y - m) * rs * gv.y + bv.y;
    o4.z = (v[i].z - m) * rs * gv.z + bv.z;
    o4.w = (v[i].w - m) * rs * gv.w + bv.w;
    op[i * 64 + l] = o4;
  }
}

template <bool GELU>
__global__ __launch_bounds__(256) void k_head_gemm(
    const float* __restrict__ in, const float* __restrict__ W,
    const float* __restrict__ bias, float* __restrict__ out, int K, int N) {
  __shared__ float partial[4][64];
  const int b = blockIdx.y;
  const int cl = threadIdx.x & 63;
  const int c = blockIdx.x * 64 + cl;
  const int kp = threadIdx.x >> 6;
  const int kc = K >> 2;
  float s = 0.f;
  if (c < N) {
    const float* ip = in + (long)b * K + kp * kc;
    const float* wp = W + (long)(kp * kc) * N + c;
    for (int k = 0; k < kc; ++k) s = fmaf(ip[k], wp[(long)k * N], s);
  }
  partial[kp][cl] = s;
  __syncthreads();
  if (kp == 0 && c < N) {
    float v = partial[0][cl] + partial[1][cl] + partial[2][cl] + partial[3][cl] +
              bias[c];
    if (GELU) v = gelu_f(v);
    out[(long)b * N + c] = v;
  }
}

extern "C" void kernel_launch(void* const* d_in, const int* in_sizes, int n_in,
                              void* d_out, int out_size, void* d_ws, size_t ws_size,
                              hipStream_t stream) {
  (void)in_sizes; (void)n_in; (void)out_size;
  if ((long)ws_size < WS_NEEDED) return;

  const float* x = (const float*)d_in[0];
  const float* Wp = (const float*)d_in[1];
  const float* bp = (const float*)d_in[2];
  const float* cls = (const float*)d_in[3];
  const float* pos = (const float*)d_in[4];
  const float* ln1g = (const float*)d_in[5];
  const float* ln1b = (const float*)d_in[6];
  const float* Wq = (const float*)d_in[7];
  const float* bq = (const float*)d_in[8];
  const float* Wk = (const float*)d_in[9];
  const float* bk = (const float*)d_in[10];
  const float* Wv = (const float*)d_in[11];
  const float* bv = (const float*)d_in[12];
  const float* Wo = (const float*)d_in[13];
  const float* bo = (const float*)d_in[14];
  const float* ln2g = (const float*)d_in[15];
  const float* ln2b = (const float*)d_in[16];
  const float* W1 = (const float*)d_in[17];
  const float* b1 = (const float*)d_in[18];
  const float* W2 = (const float*)d_in[19];
  const float* b2 = (const float*)d_in[20];
  const float* hlng = (const float*)d_in[21];
  const float* hlnb = (const float*)d_in[22];
  const float* hW1 = (const float*)d_in[23];
  const float* hb1 = (const float*)d_in[24];
  const float* hW2 = (const float*)d_in[25];
  const float* hb2 = (const float*)d_in[26];

  char* ws = (char*)d_ws;
  u16* wqkvt = (u16*)(ws + OFF_WQKVT);
  u16* wot = (u16*)(ws + OFF_WOT);
  u16* w1t = (u16*)(ws + OFF_W1T);
  u16* w2t = (u16*)(ws + OFF_W2T);
  u16* wpt = (u16*)(ws + OFF_WPT);
  float* bqkv = (float*)(ws + OFF_BQKV);
  float* h = (float*)(ws + OFF_H);
  u16* xn = (u16*)(ws + OFF_XN);
  u16* qkv = (u16*)(ws + OFF_QKV);
  u16* pbuf = qkv;
  u16* m1 = (u16*)(ws + OFF_PM1);
  float* cn = (float*)(ws + OFF_CN);
  float* t1 = (float*)(ws + OFF_T1);

  // ---- per-call weight repack ----
  k_wt64<<<dim3(2, 24, 144), dim3(32, 8), 0, stream>>>(Wq, wqkvt, 0);
  k_wt64<<<dim3(2, 24, 144), dim3(32, 8), 0, stream>>>(Wk, wqkvt, 1);
  k_wt64<<<dim3(2, 24, 144), dim3(32, 8), 0, stream>>>(Wv, wqkvt, 2);
  k_bqkv<<<108, 256, 0, stream>>>(bq, bk, bv, bqkv);
  k_transpose<<<dim3(24, 24, 12), dim3(32, 8), 0, stream>>>(Wo, wot, 768, 768);
  k_transpose<<<dim3(96, 24, 12), dim3(32, 8), 0, stream>>>(W1, w1t, 768, 3072);
  k_transpose<<<dim3(24, 96, 12), dim3(32, 8), 0, stream>>>(W2, w2t, 3072, 768);
  k_transpose<<<dim3(24, 24, 1), dim3(32, 8), 0, stream>>>(Wp, wpt, 768, 768);

  // ---- patch embed ----
  k_patchify<<<18816, 256, 0, stream>>>(x, pbuf);
  gemm2<128, 128, 2, 2, true, false, false, false, true><<<294, 256, 0, stream>>>(
      pbuf, 768, wpt, 768, h, 768, bp, nullptr, 0, 6272, 768, 768, 6);
  k_add_pos<<<4728, 256, 0, stream>>>(h, cls, pos);

  // ---- transformer layers ----
  for (int ly = 0; ly < 12; ++ly) {
    k_ln<<<1576, 256, 0, stream>>>(h, ln1g + ly * 768, ln1b + ly * 768, xn, NTOK);
    gemm_k<true, false, false, true, false><<<900, 256, 0, stream>>>(
        xn, 768, wqkvt + (long)ly * 2304 * 768, 768, qkv, 2304,
        bqkv + ly * 2304, nullptr, 0, NTOK, 2304, 768, 18);
    // fused attention: qkv -> xn (o laid out [b,s,h*64+dh])
    k_attn<<<384, 256, 0, stream>>>(qkv, xn);
    // h = o @ Wo + bo + h  (small grid -> gemm2)
    gemm2<128, 128, 2, 2, true, false, true, false, false><<<300, 256, 0, stream>>>(
        xn, 768, wot + (long)ly * 768 * 768, 768, h, 768,
        bo + ly * 768, h, 768, NTOK, 768, 768, 6);
    k_ln<<<1576, 256, 0, stream>>>(h, ln2g + ly * 768, ln2b + ly * 768, xn, NTOK);
    gemm_k<true, true, false, true, false><<<1200, 256, 0, stream>>>(
        xn, 768, w1t + (long)ly * 3072 * 768, 768, m1, 3072,
        b1 + ly * 3072, nullptr, 0, NTOK, 3072, 768, 24);
    gemm2<128, 128, 2, 2, true, false, true, false, false><<<300, 256, 0, stream>>>(
        m1, 3072, w2t + (long)ly * 768 * 3072, 3072, h, 768,
        b2 + ly * 768, h, 768, NTOK, 768, 3072, 6);
  }

  // ---- head ----
  k_head_ln<<<32, 64, 0, stream>>>(h, hlng, hlnb, cn);
  k_head_gemm<true><<<dim3(12, 32), 256, 0, stream>>>(cn, hW1, hb1, t1, 768, 768);
  k_head_gemm<false><<<dim3(16, 32), 256, 0, stream>>>(t1, hW2, hb2, (float*)d_out,
                                                       768, 1000);
}